// Round 4
// baseline (487.448 us; speedup 1.0000x reference)
//
#include <hip/hip_runtime.h>

// ---------------------------------------------------------------------------
// GCN pipeline, fp32. Round 3: channel-chunked feature layout [8][N][16] so
// each 3.2 MB chunk fits one XCD's 4 MiB L2; gather blocks pick chunk =
// blockIdx&7 (round-robin block->XCD heuristic) with a persistent grid.
// Edge metadata (src,norm) packed, nontemporal-streamed. No fp32 atomics.
// ---------------------------------------------------------------------------

typedef float nfloat4 __attribute__((ext_vector_type(4)));  // native vec for nontemporal

__global__ void hist_kernel(const int* __restrict__ dst, int* __restrict__ count, int E) {
    int e = blockIdx.x * blockDim.x + threadIdx.x;
    if (e < E) atomicAdd(&count[dst[e]], 1);
}

// pass 1: per-block inclusive scan of count -> tmp; block sums -> bsum
__global__ __launch_bounds__(256) void scan1_kernel(const int* __restrict__ count,
                                                    int* __restrict__ tmp,
                                                    int* __restrict__ bsum, int N) {
    __shared__ int s[256];
    int tid = threadIdx.x;
    int i = blockIdx.x * 256 + tid;
    int v = (i < N) ? count[i] : 0;
    s[tid] = v;
    __syncthreads();
#pragma unroll
    for (int off = 1; off < 256; off <<= 1) {
        int t = (tid >= off) ? s[tid - off] : 0;
        __syncthreads();
        s[tid] += t;
        __syncthreads();
    }
    if (i < N) tmp[i] = s[tid];
    if (tid == 255) bsum[blockIdx.x] = s[255];
}

// pass 2: exclusive scan of block sums; also zero pooled/cnt (idle capacity).
__global__ __launch_bounds__(256) void scan2_kernel(const int* __restrict__ bsum,
                                                    int* __restrict__ boff, int nb,
                                                    float* __restrict__ pooled,
                                                    float* __restrict__ cnt) {
    __shared__ int s[256];
    int tid = threadIdx.x;
    int v = (tid < nb) ? bsum[tid] : 0;
    s[tid] = v;
    __syncthreads();
#pragma unroll
    for (int off = 1; off < 256; off <<= 1) {
        int t = (tid >= off) ? s[tid - off] : 0;
        __syncthreads();
        s[tid] += t;
        __syncthreads();
    }
    if (tid < nb) boff[tid] = s[tid] - v;   // exclusive
    for (int i = tid; i < 64 * 128; i += 256) pooled[i] = 0.f;
    if (tid < 64) cnt[tid] = 0.f;
}

// pass 3: rowptr (exclusive), cursor copy, dinv
__global__ void finalize_kernel(const int* __restrict__ count, const int* __restrict__ tmp,
                                const int* __restrict__ boff, int* __restrict__ rowptr,
                                int* __restrict__ cursor, float* __restrict__ dinv, int N) {
    int i = blockIdx.x * blockDim.x + threadIdx.x;
    if (i > N) return;
    int ex = (i == 0) ? 0 : tmp[i - 1] + boff[(i - 1) >> 8];
    rowptr[i] = ex;
    if (i < N) {
        cursor[i] = ex;
        dinv[i] = 1.0f / sqrtf((float)count[i] + 1.0f);
    }
}

// reorder by dst; pack (src, norm) so the gather never touches dinv per edge.
__global__ void reorder_kernel(const int* __restrict__ src, const int* __restrict__ dst,
                               const float* __restrict__ dinv,
                               int* __restrict__ cursor, int2* __restrict__ em, int E) {
    int e = blockIdx.x * blockDim.x + threadIdx.x;
    if (e < E) {
        int s = src[e], d = dst[e];
        int pos = atomicAdd(&cursor[d], 1);
        float norm = dinv[s] * dinv[d];
        em[pos] = make_int2(s, __float_as_int(norm));
    }
}

// Persistent gather: chunk = blockIdx&7 -> XCD affinity; 4 threads/node,
// float4 per thread over the 16-channel chunk. Self-loop + bias fused.
__global__ __launch_bounds__(256) void gather_chunk(const float* __restrict__ hblk,
                                                    const float* __restrict__ dinv,
                                                    const float* __restrict__ bias,
                                                    const int* __restrict__ rowptr,
                                                    const int2* __restrict__ em,
                                                    float* __restrict__ Bblk,
                                                    int N, int ngroups) {
    int chunk = blockIdx.x & 7;
    int l = threadIdx.x & 3;                  // float4 slot in chunk
    const float* hb = hblk + (size_t)chunk * N * 16;
    float* bb = Bblk + (size_t)chunk * N * 16;
    float4 bi = *(const float4*)(bias + chunk * 16 + l * 4);
    const long long* emq = (const long long*)em;

    for (int ng = blockIdx.x >> 3; ng < ngroups; ng += 256) {
        int n = ng * 64 + (threadIdx.x >> 2);
        if (n >= N) continue;
        int beg = rowptr[n], end = rowptr[n + 1];
        float din = dinv[n];
        float selfw = din * din;
        float4 acc = *(const float4*)(hb + (size_t)n * 16 + l * 4);
        acc.x *= selfw; acc.y *= selfw; acc.z *= selfw; acc.w *= selfw;
        for (int j = beg; j < end; ++j) {
            long long v = __builtin_nontemporal_load(emq + j);
            int s = (int)(v & 0xffffffffLL);
            float nrm = __int_as_float((int)(v >> 32));
            float4 hs = *(const float4*)(hb + (size_t)s * 16 + l * 4);
            acc.x = fmaf(hs.x, nrm, acc.x);
            acc.y = fmaf(hs.y, nrm, acc.y);
            acc.z = fmaf(hs.z, nrm, acc.z);
            acc.w = fmaf(hs.w, nrm, acc.w);
        }
        nfloat4 o;
        o.x = acc.x + bi.x; o.y = acc.y + bi.y;
        o.z = acc.z + bi.z; o.w = acc.w + bi.w;
        __builtin_nontemporal_store(o, (nfloat4*)(bb + (size_t)n * 16 + l * 4));
    }
}

// C = act(X) @ W, W is 128x128. Output in chunked layout [8][M][16].
// IN_CHUNKED selects X layout: row-major [M][128] or chunked [8][M][16].
template <bool RELU_IN, bool IN_CHUNKED>
__global__ __launch_bounds__(256) void gemm128(const float* __restrict__ X,
                                               const float* __restrict__ W,
                                               float* __restrict__ OUT, int M) {
    const int BM = 64, BK = 32;
    __shared__ float Xs[BM][BK + 4];
    __shared__ float Ws[BK][128];
    int tid = threadIdx.x;
    int m0 = blockIdx.x * BM;
    int tx = tid & 15;
    int ty = tid >> 4;

    float acc[4][8];
#pragma unroll
    for (int i = 0; i < 4; i++)
#pragma unroll
        for (int j = 0; j < 8; j++) acc[i][j] = 0.f;

    for (int kk = 0; kk < 128; kk += BK) {
#pragma unroll
        for (int t = 0; t < 2; t++) {
            int idx = tid + t * 256;
            int m = idx >> 3;
            int kq = idx & 7;
            int row = m0 + m;
            int col = kk + kq * 4;
            float4 v = make_float4(0.f, 0.f, 0.f, 0.f);
            if (row < M) {
                size_t addr = IN_CHUNKED
                    ? ((size_t)(col >> 4) * M + row) * 16 + (col & 15)
                    : (size_t)row * 128 + col;
                v = *(const float4*)(X + addr);
            }
            if (RELU_IN) {
                v.x = fmaxf(v.x, 0.f); v.y = fmaxf(v.y, 0.f);
                v.z = fmaxf(v.z, 0.f); v.w = fmaxf(v.w, 0.f);
            }
            *(float4*)&Xs[m][kq * 4] = v;
        }
#pragma unroll
        for (int t = 0; t < 4; t++) {
            int idx = tid + t * 256;
            int k = idx >> 5;
            int q = idx & 31;
            float4 v = *(const float4*)(W + (size_t)(kk + k) * 128 + q * 4);
            *(float4*)&Ws[k][q * 4] = v;
        }
        __syncthreads();
#pragma unroll
        for (int k = 0; k < BK; k++) {
            float xr[4];
#pragma unroll
            for (int i = 0; i < 4; i++) xr[i] = Xs[ty * 4 + i][k];
            float4 w0 = *(const float4*)&Ws[k][tx * 8];
            float4 w1 = *(const float4*)&Ws[k][tx * 8 + 4];
            float wv[8] = {w0.x, w0.y, w0.z, w0.w, w1.x, w1.y, w1.z, w1.w};
#pragma unroll
            for (int i = 0; i < 4; i++)
#pragma unroll
                for (int j = 0; j < 8; j++)
                    acc[i][j] = fmaf(xr[i], wv[j], acc[i][j]);
        }
        __syncthreads();
    }
    // epilogue: cols tx*8 .. tx*8+7 -> chunk tx>>1, offset (tx&1)*8
#pragma unroll
    for (int i = 0; i < 4; i++) {
        int row = m0 + ty * 4 + i;
        if (row < M) {
            size_t o0 = ((size_t)(tx >> 1) * M + row) * 16 + (tx & 1) * 8;
            float4 a0 = make_float4(acc[i][0], acc[i][1], acc[i][2], acc[i][3]);
            float4 a1 = make_float4(acc[i][4], acc[i][5], acc[i][6], acc[i][7]);
            *(float4*)(OUT + o0) = a0;
            *(float4*)(OUT + o0 + 4) = a1;
        }
    }
}

// Pool over sorted batch; B in chunked layout.
__global__ __launch_bounds__(256) void pool_kernel(const float* __restrict__ Bblk,
                                                   const int* __restrict__ batch,
                                                   float* pooled, float* cnt, int N) {
    int c = threadIdx.x & 127;
    int half = threadIdx.x >> 7;
    int n0 = blockIdx.x * 128;
    size_t cbase = (size_t)(c >> 4) * N * 16 + (c & 15);
    float acc = 0.f, cacc = 0.f;
    int curg = -1;
    for (int i = half; i < 128; i += 2) {
        int n = n0 + i;
        if (n >= N) break;
        int g = batch[n];
        float v = fmaxf(Bblk[cbase + (size_t)n * 16], 0.f);
        if (g != curg) {
            if (curg >= 0) {
                atomicAdd(&pooled[curg * 128 + c], acc);
                if (c == 0) atomicAdd(&cnt[curg], cacc);
            }
            curg = g; acc = 0.f; cacc = 0.f;
        }
        acc += v; cacc += 1.f;
    }
    if (curg >= 0) {
        atomicAdd(&pooled[curg * 128 + c], acc);
        if (c == 0) atomicAdd(&cnt[curg], cacc);
    }
}

__global__ __launch_bounds__(256) void head_kernel(const float* __restrict__ pooled,
                                                   const float* __restrict__ cnt,
                                                   const float* __restrict__ Wfc1,
                                                   const float* __restrict__ bfc1,
                                                   const float* __restrict__ Wfc2,
                                                   const float* __restrict__ bfc2,
                                                   float* __restrict__ out) {
    __shared__ float mean[64 * 128];
    __shared__ float fc1[64 * 64];
    int tid = threadIdx.x;
#pragma unroll
    for (int t = 0; t < 32; t++) {
        int idx = tid + t * 256;
        int g = idx >> 7;
        mean[idx] = pooled[idx] / fmaxf(cnt[g], 1.0f);
    }
    __syncthreads();
    for (int t = 0; t < 16; t++) {
        int idx = tid + t * 256;
        int g = idx >> 6, oc = idx & 63;
        float s = bfc1[oc];
        for (int k = 0; k < 128; k++) s = fmaf(mean[g * 128 + k], Wfc1[k * 64 + oc], s);
        fc1[idx] = fmaxf(s, 0.f);
    }
    __syncthreads();
    if (tid < 64) {
        float s = bfc2[0];
        for (int k = 0; k < 64; k++) s = fmaf(fc1[tid * 64 + k], Wfc2[k], s);
        out[tid] = s;
    }
}

extern "C" void kernel_launch(void* const* d_in, const int* in_sizes, int n_in,
                              void* d_out, int out_size, void* d_ws, size_t ws_size,
                              hipStream_t stream) {
    const float* x    = (const float*)d_in[0];
    const int*   edge = (const int*)d_in[1];
    const int*   batch= (const int*)d_in[2];
    const float* W1   = (const float*)d_in[3];
    const float* b1   = (const float*)d_in[4];
    const float* W2   = (const float*)d_in[5];
    const float* b2   = (const float*)d_in[6];
    const float* Wfc1 = (const float*)d_in[7];
    const float* bfc1 = (const float*)d_in[8];
    const float* Wfc2 = (const float*)d_in[9];
    const float* bfc2 = (const float*)d_in[10];
    float* out = (float*)d_out;

    int N = in_sizes[0] / 128;
    int E = in_sizes[1] / 2;
    const int* src = edge;
    const int* dst = edge + E;

    char* ws = (char*)d_ws;
    size_t off = 0;
    auto alloc = [&](size_t bytes) { void* p = ws + off; off += (bytes + 255) & ~(size_t)255; return p; };
    float* A      = (float*)alloc((size_t)N * 128 * sizeof(float));   // chunked [8][N][16]
    float* B      = (float*)alloc((size_t)N * 128 * sizeof(float));   // chunked
    float* dinv   = (float*)alloc((size_t)N * sizeof(float));
    int*   count  = (int*)alloc((size_t)N * sizeof(int));
    int*   tmp    = (int*)alloc((size_t)N * sizeof(int));
    int*   rowptr = (int*)alloc((size_t)(N + 1) * sizeof(int));
    int*   cursor = (int*)alloc((size_t)N * sizeof(int));
    int2*  em     = (int2*)alloc((size_t)E * sizeof(int2));
    int*   bsum   = (int*)alloc(256 * sizeof(int));
    int*   boff   = (int*)alloc(256 * sizeof(int));
    float* pooled = (float*)alloc(64 * 128 * sizeof(float));
    float* cnt    = (float*)alloc(64 * sizeof(float));

    int nb = (N + 255) / 256;
    int ngroups = (N + 63) / 64;

    (void)hipMemsetAsync(count, 0, (size_t)N * sizeof(int), stream);

    // CSR build (pooled/cnt zeroed inside scan2)
    hist_kernel<<<(E + 255) / 256, 256, 0, stream>>>(dst, count, E);
    scan1_kernel<<<nb, 256, 0, stream>>>(count, tmp, bsum, N);
    scan2_kernel<<<1, 256, 0, stream>>>(bsum, boff, nb, pooled, cnt);
    finalize_kernel<<<(N + 256) / 256, 256, 0, stream>>>(count, tmp, boff, rowptr, cursor, dinv, N);
    reorder_kernel<<<(E + 255) / 256, 256, 0, stream>>>(src, dst, dinv, cursor, em, E);

    int gblocks = (N + 63) / 64;

    // Layer 1
    gemm128<false, false><<<gblocks, 256, 0, stream>>>(x, W1, A, N);
    gather_chunk<<<2048, 256, 0, stream>>>(A, dinv, b1, rowptr, em, B, N, ngroups);

    // Layer 2 (relu fused into GEMM input read)
    gemm128<true, true><<<gblocks, 256, 0, stream>>>(B, W2, A, N);
    gather_chunk<<<2048, 256, 0, stream>>>(A, dinv, b2, rowptr, em, B, N, ngroups);

    // Pool (relu fused) + head
    pool_kernel<<<(N + 127) / 128, 256, 0, stream>>>(B, batch, pooled, cnt, N);
    head_kernel<<<1, 256, 0, stream>>>(pooled, cnt, Wfc1, bfc1, Wfc2, bfc2, out);
}

// Round 5
// 356.029 us; speedup vs baseline: 1.3691x; 1.3691x over previous
//
#include <hip/hip_runtime.h>

// ---------------------------------------------------------------------------
// GCN pipeline. Round 5:
//  - GEMMs via bf16x3 split MFMA (fp32-accurate to ~1e-5; no fp32 MFMA on CDNA4)
//  - gather: row-layout, wave/node, wave-uniform edge-meta loads, 4x unroll
//  - head parallelized across 64 graphs
// ---------------------------------------------------------------------------

typedef short bf16x8 __attribute__((ext_vector_type(8)));   // MFMA A/B frag (8 bf16)
typedef float f32x4  __attribute__((ext_vector_type(4)));   // MFMA C/D frag

__device__ inline unsigned short f2bf_rne(float f) {
    unsigned u = __float_as_uint(f);
    unsigned r = (u + 0x7fffu + ((u >> 16) & 1u)) >> 16;
    return (unsigned short)r;
}
__device__ inline float bf2f(unsigned short h) {
    return __uint_as_float(((unsigned)h) << 16);
}

__global__ void hist_kernel(const int* __restrict__ dst, int* __restrict__ count, int E) {
    int e = blockIdx.x * blockDim.x + threadIdx.x;
    if (e < E) atomicAdd(&count[dst[e]], 1);
}

__global__ __launch_bounds__(256) void scan1_kernel(const int* __restrict__ count,
                                                    int* __restrict__ tmp,
                                                    int* __restrict__ bsum, int N) {
    __shared__ int s[256];
    int tid = threadIdx.x;
    int i = blockIdx.x * 256 + tid;
    int v = (i < N) ? count[i] : 0;
    s[tid] = v;
    __syncthreads();
#pragma unroll
    for (int off = 1; off < 256; off <<= 1) {
        int t = (tid >= off) ? s[tid - off] : 0;
        __syncthreads();
        s[tid] += t;
        __syncthreads();
    }
    if (i < N) tmp[i] = s[tid];
    if (tid == 255) bsum[blockIdx.x] = s[255];
}

__global__ __launch_bounds__(256) void scan2_kernel(const int* __restrict__ bsum,
                                                    int* __restrict__ boff, int nb,
                                                    float* __restrict__ pooled,
                                                    float* __restrict__ cnt) {
    __shared__ int s[256];
    int tid = threadIdx.x;
    int v = (tid < nb) ? bsum[tid] : 0;
    s[tid] = v;
    __syncthreads();
#pragma unroll
    for (int off = 1; off < 256; off <<= 1) {
        int t = (tid >= off) ? s[tid - off] : 0;
        __syncthreads();
        s[tid] += t;
        __syncthreads();
    }
    if (tid < nb) boff[tid] = s[tid] - v;   // exclusive
    for (int i = tid; i < 64 * 128; i += 256) pooled[i] = 0.f;
    if (tid < 64) cnt[tid] = 0.f;
}

__global__ void finalize_kernel(const int* __restrict__ count, const int* __restrict__ tmp,
                                const int* __restrict__ boff, int* __restrict__ rowptr,
                                int* __restrict__ cursor, float* __restrict__ dinv, int N) {
    int i = blockIdx.x * blockDim.x + threadIdx.x;
    if (i > N) return;
    int ex = (i == 0) ? 0 : tmp[i - 1] + boff[(i - 1) >> 8];
    rowptr[i] = ex;
    if (i < N) {
        cursor[i] = ex;
        dinv[i] = 1.0f / sqrtf((float)count[i] + 1.0f);
    }
}

__global__ void reorder_kernel(const int* __restrict__ src, const int* __restrict__ dst,
                               const float* __restrict__ dinv,
                               int* __restrict__ cursor, int2* __restrict__ em, int E) {
    int e = blockIdx.x * blockDim.x + threadIdx.x;
    if (e < E) {
        int s = src[e], d = dst[e];
        int pos = atomicAdd(&cursor[d], 1);
        float norm = dinv[s] * dinv[d];
        em[pos] = make_int2(s, __float_as_int(norm));
    }
}

// W [128][128] fp32 row-major -> transposed bf16 hi/lo Wt[n][k]
__global__ __launch_bounds__(256) void wconv_kernel(const float* __restrict__ W,
                                                    unsigned short* __restrict__ Whi,
                                                    unsigned short* __restrict__ Wlo) {
    int i = blockIdx.x * 256 + threadIdx.x;   // 0..16383
    int k = i >> 7, n = i & 127;
    float v = W[i];
    unsigned short h = f2bf_rne(v);
    float lo = v - bf2f(h);
    Whi[n * 128 + k] = h;
    Wlo[n * 128 + k] = f2bf_rne(lo);
}

// C[M,128] = act(X)[M,128] @ W ; W given pre-transposed+split (Wt[n][k] bf16).
// bf16x3: C = Ah*Bh + Al*Bh + Ah*Bl. 4 waves/block, wave w -> rows w*16..+16.
template <bool RELU_IN>
__global__ __launch_bounds__(256) void gemm_mfma(const float* __restrict__ X,
                                                 const unsigned short* __restrict__ Wthi,
                                                 const unsigned short* __restrict__ Wtlo,
                                                 float* __restrict__ OUT, int M) {
    int w = threadIdx.x >> 6;
    int l = threadIdx.x & 63;
    int m0 = blockIdx.x * 64 + w * 16;
    int mrow = m0 + (l & 15);
    int arow = (mrow < M) ? mrow : (M - 1);
    int q = l >> 4;                       // 0..3 (k-subblock)
    int nn = l & 15;                      // col within tile / row within A-tile

    f32x4 acc[8];
#pragma unroll
    for (int ct = 0; ct < 8; ct++) acc[ct] = (f32x4){0.f, 0.f, 0.f, 0.f};

#pragma unroll
    for (int ks = 0; ks < 4; ks++) {
        const float* ap = X + (size_t)arow * 128 + ks * 32 + q * 8;
        float4 a0 = *(const float4*)ap;
        float4 a1 = *(const float4*)(ap + 4);
        float av[8] = {a0.x, a0.y, a0.z, a0.w, a1.x, a1.y, a1.z, a1.w};
        bf16x8 ahi, alo;
#pragma unroll
        for (int j = 0; j < 8; j++) {
            float v = RELU_IN ? fmaxf(av[j], 0.f) : av[j];
            unsigned short h = f2bf_rne(v);
            ahi[j] = (short)h;
            alo[j] = (short)f2bf_rne(v - bf2f(h));
        }
#pragma unroll
        for (int ct = 0; ct < 8; ct++) {
            size_t boffs = (size_t)(ct * 16 + nn) * 128 + ks * 32 + q * 8;
            bf16x8 bhi = *(const bf16x8*)(Wthi + boffs);
            bf16x8 blo = *(const bf16x8*)(Wtlo + boffs);
            acc[ct] = __builtin_amdgcn_mfma_f32_16x16x32_bf16(ahi, bhi, acc[ct], 0, 0, 0);
            acc[ct] = __builtin_amdgcn_mfma_f32_16x16x32_bf16(alo, bhi, acc[ct], 0, 0, 0);
            acc[ct] = __builtin_amdgcn_mfma_f32_16x16x32_bf16(ahi, blo, acc[ct], 0, 0, 0);
        }
    }
    // C/D layout: col = l&15, row = (l>>4)*4 + r  (within the wave's 16-row tile)
#pragma unroll
    for (int r = 0; r < 4; r++) {
        int row = m0 + q * 4 + r;
        if (row < M) {
#pragma unroll
            for (int ct = 0; ct < 8; ct++)
                OUT[(size_t)row * 128 + ct * 16 + nn] = acc[ct][r];
        }
    }
}

// Wave per node; lane covers 2 channels. Wave-uniform em reads, 4x unroll.
__global__ __launch_bounds__(256) void gather_row(const float* __restrict__ h,
                                                  const float* __restrict__ dinv,
                                                  const float* __restrict__ bias,
                                                  const int* __restrict__ rowptr,
                                                  const long long* __restrict__ em,
                                                  float* __restrict__ B, int N) {
    int n = blockIdx.x * 4 + (threadIdx.x >> 6);
    int lane = threadIdx.x & 63;
    if (n >= N) return;
    int beg = rowptr[n], end = rowptr[n + 1];
    float din = dinv[n];
    const float2* hp = (const float2*)h;
    float2 hv = hp[(size_t)n * 64 + lane];
    float sw = din * din;
    float ax = hv.x * sw, ay = hv.y * sw;
    int j = beg;
    for (; j + 4 <= end; j += 4) {
        long long v0 = em[j], v1 = em[j + 1], v2 = em[j + 2], v3 = em[j + 3];
        int s0 = (int)v0, s1 = (int)v1, s2 = (int)v2, s3 = (int)v3;
        float n0 = __int_as_float((int)(v0 >> 32));
        float n1 = __int_as_float((int)(v1 >> 32));
        float n2 = __int_as_float((int)(v2 >> 32));
        float n3 = __int_as_float((int)(v3 >> 32));
        float2 r0 = hp[(size_t)s0 * 64 + lane];
        float2 r1 = hp[(size_t)s1 * 64 + lane];
        float2 r2 = hp[(size_t)s2 * 64 + lane];
        float2 r3 = hp[(size_t)s3 * 64 + lane];
        ax = fmaf(r0.x, n0, ax); ay = fmaf(r0.y, n0, ay);
        ax = fmaf(r1.x, n1, ax); ay = fmaf(r1.y, n1, ay);
        ax = fmaf(r2.x, n2, ax); ay = fmaf(r2.y, n2, ay);
        ax = fmaf(r3.x, n3, ax); ay = fmaf(r3.y, n3, ay);
    }
    for (; j < end; j++) {
        long long v = em[j];
        int s = (int)v;
        float nr = __int_as_float((int)(v >> 32));
        float2 r = hp[(size_t)s * 64 + lane];
        ax = fmaf(r.x, nr, ax); ay = fmaf(r.y, nr, ay);
    }
    float2 o;
    o.x = ax + bias[lane * 2];
    o.y = ay + bias[lane * 2 + 1];
    *(float2*)(B + (size_t)n * 128 + lane * 2) = o;
}

// Pool: batch sorted -> run-length accumulate, atomics only at transitions.
__global__ __launch_bounds__(256) void pool_kernel(const float* __restrict__ B,
                                                   const int* __restrict__ batch,
                                                   float* pooled, float* cnt, int N) {
    int c = threadIdx.x & 127;
    int half = threadIdx.x >> 7;
    int n0 = blockIdx.x * 128;
    float acc = 0.f, cacc = 0.f;
    int curg = -1;
    for (int i = half; i < 128; i += 2) {
        int n = n0 + i;
        if (n >= N) break;
        int g = batch[n];
        float v = fmaxf(B[(size_t)n * 128 + c], 0.f);
        if (g != curg) {
            if (curg >= 0) {
                atomicAdd(&pooled[curg * 128 + c], acc);
                if (c == 0) atomicAdd(&cnt[curg], cacc);
            }
            curg = g; acc = 0.f; cacc = 0.f;
        }
        acc += v; cacc += 1.f;
    }
    if (curg >= 0) {
        atomicAdd(&pooled[curg * 128 + c], acc);
        if (c == 0) atomicAdd(&cnt[curg], cacc);
    }
}

// One block (1 wave of 64) per graph: mean -> fc1(relu) -> fc2.
__global__ __launch_bounds__(64) void head_kernel(const float* __restrict__ pooled,
                                                  const float* __restrict__ cnt,
                                                  const float* __restrict__ Wfc1,
                                                  const float* __restrict__ bfc1,
                                                  const float* __restrict__ Wfc2,
                                                  const float* __restrict__ bfc2,
                                                  float* __restrict__ out) {
    __shared__ float mean[128];
    int g = blockIdx.x;
    int t = threadIdx.x;
    float inv = 1.0f / fmaxf(cnt[g], 1.0f);
    mean[t] = pooled[g * 128 + t] * inv;
    mean[t + 64] = pooled[g * 128 + t + 64] * inv;
    __syncthreads();
    float s = bfc1[t];
#pragma unroll 4
    for (int k = 0; k < 128; k++) s = fmaf(mean[k], Wfc1[k * 64 + t], s);
    float p = fmaxf(s, 0.f) * Wfc2[t];
#pragma unroll
    for (int o = 32; o > 0; o >>= 1) p += __shfl_down(p, o, 64);
    if (t == 0) out[g] = p + bfc2[0];
}

extern "C" void kernel_launch(void* const* d_in, const int* in_sizes, int n_in,
                              void* d_out, int out_size, void* d_ws, size_t ws_size,
                              hipStream_t stream) {
    const float* x    = (const float*)d_in[0];
    const int*   edge = (const int*)d_in[1];
    const int*   batch= (const int*)d_in[2];
    const float* W1   = (const float*)d_in[3];
    const float* b1   = (const float*)d_in[4];
    const float* W2   = (const float*)d_in[5];
    const float* b2   = (const float*)d_in[6];
    const float* Wfc1 = (const float*)d_in[7];
    const float* bfc1 = (const float*)d_in[8];
    const float* Wfc2 = (const float*)d_in[9];
    const float* bfc2 = (const float*)d_in[10];
    float* out = (float*)d_out;

    int N = in_sizes[0] / 128;
    int E = in_sizes[1] / 2;
    const int* src = edge;
    const int* dst = edge + E;

    char* ws = (char*)d_ws;
    size_t off = 0;
    auto alloc = [&](size_t bytes) { void* p = ws + off; off += (bytes + 255) & ~(size_t)255; return p; };
    float* A      = (float*)alloc((size_t)N * 128 * sizeof(float));   // gemm out [N][128]
    float* B      = (float*)alloc((size_t)N * 128 * sizeof(float));   // gather out
    float* dinv   = (float*)alloc((size_t)N * sizeof(float));
    int*   count  = (int*)alloc((size_t)N * sizeof(int));
    int*   tmp    = (int*)alloc((size_t)N * sizeof(int));
    int*   rowptr = (int*)alloc((size_t)(N + 1) * sizeof(int));
    int*   cursor = (int*)alloc((size_t)N * sizeof(int));
    int2*  em     = (int2*)alloc((size_t)E * sizeof(int2));
    int*   bsum   = (int*)alloc(256 * sizeof(int));
    int*   boff   = (int*)alloc(256 * sizeof(int));
    float* pooled = (float*)alloc(64 * 128 * sizeof(float));
    float* cnt    = (float*)alloc(64 * sizeof(float));
    unsigned short* Wt1h = (unsigned short*)alloc(128 * 128 * sizeof(short));
    unsigned short* Wt1l = (unsigned short*)alloc(128 * 128 * sizeof(short));
    unsigned short* Wt2h = (unsigned short*)alloc(128 * 128 * sizeof(short));
    unsigned short* Wt2l = (unsigned short*)alloc(128 * 128 * sizeof(short));

    int nb = (N + 255) / 256;

    (void)hipMemsetAsync(count, 0, (size_t)N * sizeof(int), stream);

    // CSR build (pooled/cnt zeroed inside scan2) + weight split/transpose
    hist_kernel<<<(E + 255) / 256, 256, 0, stream>>>(dst, count, E);
    scan1_kernel<<<nb, 256, 0, stream>>>(count, tmp, bsum, N);
    scan2_kernel<<<1, 256, 0, stream>>>(bsum, boff, nb, pooled, cnt);
    finalize_kernel<<<(N + 256) / 256, 256, 0, stream>>>(count, tmp, boff, rowptr, cursor, dinv, N);
    reorder_kernel<<<(E + 255) / 256, 256, 0, stream>>>(src, dst, dinv, cursor, em, E);
    wconv_kernel<<<64, 256, 0, stream>>>(W1, Wt1h, Wt1l);
    wconv_kernel<<<64, 256, 0, stream>>>(W2, Wt2h, Wt2l);

    int gblocks = (N + 63) / 64;
    int ablocks = (N + 3) / 4;

    // Layer 1
    gemm_mfma<false><<<gblocks, 256, 0, stream>>>(x, Wt1h, Wt1l, A, N);
    gather_row<<<ablocks, 256, 0, stream>>>(A, dinv, b1, rowptr, (const long long*)em, B, N);

    // Layer 2 (relu fused into GEMM input split)
    gemm_mfma<true><<<gblocks, 256, 0, stream>>>(B, Wt2h, Wt2l, A, N);
    gather_row<<<ablocks, 256, 0, stream>>>(A, dinv, b2, rowptr, (const long long*)em, B, N);

    // Pool (relu fused) + head (one wave per graph)
    pool_kernel<<<(N + 127) / 128, 256, 0, stream>>>(B, batch, pooled, cnt, N);
    head_kernel<<<64, 64, 0, stream>>>(pooled, cnt, Wfc1, bfc1, Wfc2, bfc2, out);
}